// Round 4
// baseline (1436.153 us; speedup 1.0000x reference)
//
#include <hip/hip_runtime.h>

// Problem: B=256, T=512, I=64, H=512.  h_t = tanh(x_t@Wxh + b + h@Whh); out = h_T@fc_w.T + fc_b
//
// R4 design ("rnn_smem"): the R2/R3 structure was LDS-return-bus bound: every thread needs all
// 512 h values per step (1 KB/thread -> 512 KB/step/CU through the 256 B/cyc LDS bus = 2048 cyc
// floor). Bypass: feed h through the SCALAR operand bus. v_dot2_f32_f16 takes one SGPR source;
// h lives in a rotating global ring read via addrspace(4) uniform loads -> s_load_dwordxN.
//  - 1024 thr/block, wave-uniform K-half split (kh = tid>>9) over K=576 = [h(512); x_t(64)]
//    (x folded in -> no separate xh GEMM pass).
//  - weights: 108 half2 pairs in VGPRs (allocator caps arch at 128 - observed R2/R3) + 36 pairs
//    in LDS chunk-major [c][tid] (conflict-free b128), 144 KB.
//  - h ring: 64 rows x 1152 B per block in d_ws. Rotation (64 KB >> 16 KB scalar L1) makes
//    stale-K$ hits impossible; __syncthreads' vmcnt(0) drain + same-XCD L2 gives visibility.
//  - base pointer laundered per step via readfirstlane (guaranteed wave-uniform for SMEM
//    selection; blocks cross-step CSE of "constant" loads).

#define BATCH    256
#define TSTEPS   512
#define IDIM     64
#define HDIM     512
#define KEXT     576
#define KHALF    288            // K per thread (u32 pairs: 144)
#define NTH      1024
#define RP       108            // reg pairs per thread
#define LP       36             // LDS pairs per thread (9 chunks x 4)
#define LCH      9              // LDS b128 chunks per thread
#define DEPTH    64             // h-ring rotation depth (pow2)
#define ROWB     1152           // bytes per ring row = 576 halfs

#define LDSW_BYTES (LCH * 16 * NTH)              // 147456
#define PSCR_OFF   LDSW_BYTES                    // 512 floats
#define RED_OFF    (PSCR_OFF + HDIM * 4)         // 16 floats
#define SMEM_BYTES (RED_OFF + 64)                // 149568

typedef _Float16 half2_t __attribute__((ext_vector_type(2)));
typedef _Float16 half8_t __attribute__((ext_vector_type(8)));
typedef const __attribute__((address_space(4))) unsigned int* cu4p;

union H8U {
    half8_t v;
    half2_t p[4];
    uint4   u4;
};

__device__ __forceinline__ float fdot2(half2_t a, half2_t b, float c) {
#if __has_builtin(__builtin_amdgcn_fdot2)
    return __builtin_amdgcn_fdot2(a, b, c, false);
#else
    return c + (float)a[0] * (float)b[0] + (float)a[1] * (float)b[1];
#endif
}

__device__ __forceinline__ float fast_tanh(float x) {
    float e = __builtin_amdgcn_exp2f(x * 2.88539008177792681472f);
    return 1.0f - 2.0f * __builtin_amdgcn_rcpf(e + 1.0f);
}

__device__ __forceinline__ float ldW(const float* __restrict__ Whh,
                                     const float* __restrict__ Wxh, int k, int j) {
    return k < HDIM ? Whh[(size_t)k * HDIM + j] : Wxh[(size_t)(k - HDIM) * HDIM + j];
}

__device__ __forceinline__ half2_t bc_h2(unsigned int u) {
    union { unsigned int u; half2_t h; } c;
    c.u = u;
    return c.h;
}

__global__ __launch_bounds__(NTH)
void rnn_smem(const float* __restrict__ x,    // (B,T,I)
              const float* __restrict__ Wxh,  // (I,H)
              const float* __restrict__ Whh,  // (H,H)
              const float* __restrict__ bias, // (H)
              const float* __restrict__ fcw,  // (1,H)
              const float* __restrict__ fcb,  // (1)
              _Float16* __restrict__ hring,   // (B, DEPTH, 576) in d_ws
              float* __restrict__ out)        // (B,1)
{
    extern __shared__ char smem[];
    uint4* ldsW = reinterpret_cast<uint4*>(smem);
    float* pscr = reinterpret_cast<float*>(smem + PSCR_OFF);
    float* red  = reinterpret_cast<float*>(smem + RED_OFF);

    const int tid = threadIdx.x;
    const int kh  = tid >> 9;        // 0/1, wave-uniform (waves 0-7 vs 8-15)
    const int j   = tid & (HDIM - 1);
    const int b   = blockIdx.x;
    const int khm = kh * KHALF;      // half-index base of this thread's K range

    // ---- Prologue: weights for K range [khm, khm+288) of column j ----
    half2_t wreg[RP];
#pragma unroll
    for (int p = 0; p < RP; ++p) {
        const int k = khm + 2 * p;
        half2_t w;
        w[0] = (_Float16)ldW(Whh, Wxh, k, j);
        w[1] = (_Float16)ldW(Whh, Wxh, k + 1, j);
        wreg[p] = w;
    }
#pragma unroll
    for (int c = 0; c < LCH; ++c) {
        H8U u;
#pragma unroll
        for (int q = 0; q < 4; ++q) {
            const int m = RP + 4 * c + q;     // pair index in [108,144)
            const int k = khm + 2 * m;
            half2_t w;
            w[0] = (_Float16)ldW(Whh, Wxh, k, j);
            w[1] = (_Float16)ldW(Whh, Wxh, k + 1, j);
            u.p[q] = w;
        }
        ldsW[c * NTH + tid] = u.u4;           // chunk-major: conflict-free b128
    }

    const float bj   = bias[j];
    const float fcwj = fcw[j];

    _Float16* hrows = hring + (size_t)b * DEPTH * KEXT;

    // ---- Step-0 staging into ring slot 0: h=0, x_0 appended ----
    if (!kh) {
        hrows[j] = (_Float16)0.0f;
    } else if (j < IDIM) {
        hrows[HDIM + j] = (_Float16)x[((size_t)b * TSTEPS + 0) * IDIM + j];
    }
    __syncthreads();   // drains stores (vmcnt 0) -> visible in L2 for s_loads

    // Per-wave scalar base (bytes): ring base + this K-half's offset.
    const uintptr_t praw = (uintptr_t)hrows + (size_t)khm * 2;

    float hval = 0.0f;
    for (int t = 0; t < TSTEPS; ++t) {
        // Launder base: readfirstlane => guaranteed wave-uniform (SMEM-selectable),
        // and a fresh opaque value each step (no cross-step load CSE).
        unsigned int lo = __builtin_amdgcn_readfirstlane((unsigned int)praw);
        unsigned int hi = __builtin_amdgcn_readfirstlane((unsigned int)(praw >> 32));
        const uintptr_t laund = ((uintptr_t)hi << 32) | (uintptr_t)lo;
        cu4p hrow = (cu4p)(laund + (size_t)(t & (DEPTH - 1)) * ROWB);

        // Prefetch next x_t (kh=1, j<64) early; stored at publish time.
        float xnext = 0.0f;
        const bool dox = kh && (j < IDIM) && (t + 1 < TSTEPS);
        if (dox) xnext = x[((size_t)b * TSTEPS + (t + 1)) * IDIM + j];

        float a0 = 0.0f, a1 = 0.0f, a2 = 0.0f, a3 = 0.0f;
        // Register-weight part: h pairs from SGPRs (scalar bus), weights from VGPRs.
#pragma unroll
        for (int p = 0; p < RP; p += 4) {
            a0 = fdot2(bc_h2(hrow[p + 0]), wreg[p + 0], a0);
            a1 = fdot2(bc_h2(hrow[p + 1]), wreg[p + 1], a1);
            a2 = fdot2(bc_h2(hrow[p + 2]), wreg[p + 2], a2);
            a3 = fdot2(bc_h2(hrow[p + 3]), wreg[p + 3], a3);
        }
        // LDS-weight part.
#pragma unroll
        for (int c = 0; c < LCH; ++c) {
            const uint4 wv = ldsW[c * NTH + tid];
            const int m = RP + 4 * c;
            a0 = fdot2(bc_h2(hrow[m + 0]), bc_h2(wv.x), a0);
            a1 = fdot2(bc_h2(hrow[m + 1]), bc_h2(wv.y), a1);
            a2 = fdot2(bc_h2(hrow[m + 2]), bc_h2(wv.z), a2);
            a3 = fdot2(bc_h2(hrow[m + 3]), bc_h2(wv.w), a3);
        }
        const float aa = (a0 + a1) + (a2 + a3);

        if (kh) pscr[j] = aa;                 // kh=1 publishes its partial
        __syncthreads();

        const int nslot = (t + 1) & (DEPTH - 1);
        if (!kh) {
            const float tot = aa + pscr[j] + bj;
            hval = fast_tanh(tot);
            if (t + 1 < TSTEPS)
                hrows[(size_t)nslot * KEXT + j] = (_Float16)hval;
        } else if (dox) {
            hrows[(size_t)nslot * KEXT + HDIM + j] = (_Float16)xnext;
        }
        __syncthreads();   // drain h/x stores before next step's scalar loads
    }

    // ---- Epilogue: out[b] = sum_j h_T[j]*fc_w[j] + fc_b ----
    float partial = (!kh) ? hval * fcwj : 0.0f;
#pragma unroll
    for (int off = 32; off >= 1; off >>= 1)
        partial += __shfl_down(partial, off, 64);
    if ((tid & 63) == 0) red[tid >> 6] = partial;
    __syncthreads();
    if (tid == 0) {
        float s = 0.0f;
#pragma unroll
        for (int w = 0; w < 16; ++w) s += red[w];
        out[b] = s + fcb[0];
    }
}

// ============================= fused fallback (K=576, emergency only) =============================
#define F_NTH  512
#define F_RP   216
#define F_RC   54
#define F_LC   18
#define F_LSTR 19
#define F_LDSW_BYTES (512 * F_LSTR * 16)
#define F_HBUF_OFF   F_LDSW_BYTES
#define F_HBUF_ELEMS 640
#define F_RED_OFF    (F_HBUF_OFF + 2 * F_HBUF_ELEMS * 2)
#define F_SMEM_BYTES (F_RED_OFF + 64)

__global__ __attribute__((amdgpu_flat_work_group_size(F_NTH, F_NTH), amdgpu_waves_per_eu(2, 2)))
void rnn_fused(const float* __restrict__ x, const float* __restrict__ Wxh,
               const float* __restrict__ Whh, const float* __restrict__ bias,
               const float* __restrict__ fcw, const float* __restrict__ fcb,
               float* __restrict__ out)
{
    extern __shared__ char smem[];
    uint4*    ldsW = reinterpret_cast<uint4*>(smem);
    _Float16* hbuf = reinterpret_cast<_Float16*>(smem + F_HBUF_OFF);
    float*    red  = reinterpret_cast<float*>(smem + F_RED_OFF);

    const int j = threadIdx.x;
    const int b = blockIdx.x;

    half2_t wreg[F_RP];
#pragma unroll
    for (int p = 0; p < F_RP; ++p) {
        const int k = 2 * p;
        half2_t w;
        w[0] = (_Float16)Whh[(size_t)k * HDIM + j];
        w[1] = (_Float16)Whh[(size_t)(k + 1) * HDIM + j];
        wreg[p] = w;
    }
#pragma unroll
    for (int cc = 0; cc < F_LC; ++cc) {
        H8U u;
#pragma unroll
        for (int q = 0; q < 4; ++q) {
            const int k0 = 432 + 8 * cc + 2 * q;
            half2_t w;
            w[0] = (_Float16)ldW(Whh, Wxh, k0, j);
            w[1] = (_Float16)ldW(Whh, Wxh, k0 + 1, j);
            u.p[q] = w;
        }
        ldsW[j * F_LSTR + cc] = u.u4;
    }

    const float bj   = bias[j];
    const float fcwj = fcw[j];

    hbuf[j] = (_Float16)0.0f;
    if (j < IDIM) hbuf[HDIM + j] = (_Float16)x[((size_t)b * TSTEPS + 0) * IDIM + j];
    __syncthreads();

    float hval = 0.0f;
    for (int t = 0; t < TSTEPS; ++t) {
        const int cur = t & 1;
        const int nxt = cur ^ 1;
        const _Float16* hb = hbuf + cur * F_HBUF_ELEMS;

        float xv = 0.0f;
        const bool do_x = (j < IDIM) && (t + 1 < TSTEPS);
        if (do_x) xv = x[((size_t)b * TSTEPS + (t + 1)) * IDIM + j];

        float a0 = bj, a1 = 0.0f, a2 = 0.0f, a3 = 0.0f;
#pragma unroll
        for (int c = 0; c < F_RC; ++c) {
            H8U u;
            u.v = *reinterpret_cast<const half8_t*>(hb + 8 * c);
            a0 = fdot2(u.p[0], wreg[4 * c + 0], a0);
            a1 = fdot2(u.p[1], wreg[4 * c + 1], a1);
            a2 = fdot2(u.p[2], wreg[4 * c + 2], a2);
            a3 = fdot2(u.p[3], wreg[4 * c + 3], a3);
        }
#pragma unroll
        for (int cc = 0; cc < F_LC; ++cc) {
            H8U u, w;
            u.v  = *reinterpret_cast<const half8_t*>(hb + 8 * (F_RC + cc));
            w.u4 = ldsW[j * F_LSTR + cc];
            a0 = fdot2(u.p[0], w.p[0], a0);
            a1 = fdot2(u.p[1], w.p[1], a1);
            a2 = fdot2(u.p[2], w.p[2], a2);
            a3 = fdot2(u.p[3], w.p[3], a3);
        }
        hval = fast_tanh((a0 + a1) + (a2 + a3));

        hbuf[nxt * F_HBUF_ELEMS + j] = (_Float16)hval;
        if (do_x) hbuf[nxt * F_HBUF_ELEMS + HDIM + j] = (_Float16)xv;
        __syncthreads();
    }

    float partial = hval * fcwj;
#pragma unroll
    for (int off = 32; off >= 1; off >>= 1)
        partial += __shfl_down(partial, off, 64);
    if ((j & 63) == 0) red[j >> 6] = partial;
    __syncthreads();
    if (j == 0) {
        float s = 0.0f;
#pragma unroll
        for (int w = 0; w < 8; ++w) s += red[w];
        out[b] = s + fcb[0];
    }
}

// ============================= host =============================
extern "C" void kernel_launch(void* const* d_in, const int* in_sizes, int n_in,
                              void* d_out, int out_size, void* d_ws, size_t ws_size,
                              hipStream_t stream) {
    const float* x    = (const float*)d_in[0];
    const float* Wxh  = (const float*)d_in[1];
    const float* Whh  = (const float*)d_in[2];
    const float* bias = (const float*)d_in[3];
    const float* fcw  = (const float*)d_in[4];
    const float* fcb  = (const float*)d_in[5];
    float* out = (float*)d_out;

    const size_t ring_bytes = (size_t)BATCH * DEPTH * ROWB;   // 18.9 MB
    if (ws_size >= ring_bytes) {
        hipFuncSetAttribute(reinterpret_cast<const void*>(rnn_smem),
                            hipFuncAttributeMaxDynamicSharedMemorySize, SMEM_BYTES);
        _Float16* hring = (_Float16*)d_ws;
        rnn_smem<<<BATCH, NTH, SMEM_BYTES, stream>>>(x, Wxh, Whh, bias, fcw, fcb, hring, out);
    } else {
        hipFuncSetAttribute(reinterpret_cast<const void*>(rnn_fused),
                            hipFuncAttributeMaxDynamicSharedMemorySize, F_SMEM_BYTES);
        rnn_fused<<<BATCH, F_NTH, F_SMEM_BYTES, stream>>>(x, Wxh, Whh, bias, fcw, fcb, out);
    }
}

// Round 5
// 1242.372 us; speedup vs baseline: 1.1560x; 1.1560x over previous
//
#include <hip/hip_runtime.h>

// B=256, T=512, I=64, H=512.  h_t = tanh(xh_t + h@Whh); out = h_T@fc_w.T + fc_b
//
// R5 "rnn_mfma": move the recurrent GEMV to the matrix core.
//  - xh = x@Wxh + b precomputed fp16 into d_ws (as R2, proven).
//  - 256 blocks (1 batch row/CU), 512 thr = 8 waves, waves_per_eu(2,2) -> 256 reg slots/wave
//    (R2/R3-proven spill-free config; AGPR overflow is FREE for MFMA operands).
//  - wave w owns cols [64w,64w+64): 4 n-tiles x 16 k-tiles of v_mfma_f32_16x16x32_f16.
//    B-frags: k-tiles 0..11 in registers (192 slots), k-tiles 12..15 in LDS (131 KB).
//  - M=1 trick: only D row 0 is read, so lanes with (lane&15)!=0 may carry duplicate A data;
//    they only pollute D rows 1..15 (ignored). No lane masking anywhere.
//  - h double-buffered in LDS (2x512 fp16), ONE barrier per step.

#define BATCH    256
#define TSTEPS   512
#define IDIM     64
#define HDIM     512
#define NTH      512
#define WAVES    8
#define NT       4            // n-tiles per wave (16 cols each)
#define RKT      12           // k-tiles with B-frags in registers
#define LKT      4            // k-tiles with B-frags in LDS
#define KT       16           // total k-tiles (K=512)

#define LDSW_BYTES (WAVES * NT * LKT * 64 * 16)   // 131072
#define HB_OFF     LDSW_BYTES                     // 2 x 512 fp16 = 2048 B
#define RED_OFF    (HB_OFF + 2 * HDIM * 2)
#define SMEM_BYTES (RED_OFF + 64)                 // 133184 <= 160K

typedef _Float16 half2_t  __attribute__((ext_vector_type(2)));
typedef _Float16 half8_t  __attribute__((ext_vector_type(8)));
typedef float    float4_t __attribute__((ext_vector_type(4)));

union H8U {
    half8_t  v;
    half2_t  p[4];
    uint4    u4;
    _Float16 e[8];
};

__device__ __forceinline__ float fast_tanh(float x) {
    float e = __builtin_amdgcn_exp2f(x * 2.88539008177792681472f);
    return 1.0f - 2.0f * __builtin_amdgcn_rcpf(e + 1.0f);
}

// ============================= xh precompute (R2-proven) =============================
#define XH_ROWS 16
__global__ __launch_bounds__(NTH, 4)
void xh_gemm(const float* __restrict__ x, const float* __restrict__ Wxh,
             const float* __restrict__ bias, _Float16* __restrict__ xh)
{
    const int j = threadIdx.x;
    const size_t r0 = (size_t)blockIdx.x * XH_ROWS;
    float wcol[IDIM];
#pragma unroll
    for (int i = 0; i < IDIM; ++i) wcol[i] = Wxh[(size_t)i * HDIM + j];
    const float bj = bias[j];
#pragma unroll
    for (int r = 0; r < XH_ROWS; ++r) {
        const float* xr = x + (r0 + r) * IDIM;
        float acc = bj;
#pragma unroll
        for (int i = 0; i < IDIM; ++i) acc += xr[i] * wcol[i];
        xh[(r0 + r) * HDIM + j] = (_Float16)acc;
    }
}

// ============================= MFMA recurrent kernel =============================
__global__ __attribute__((amdgpu_flat_work_group_size(NTH, NTH), amdgpu_waves_per_eu(2, 2)))
void rnn_mfma(const _Float16* __restrict__ xh,  // (B*T, H) fp16, bias folded
              const float* __restrict__ Whh,    // (H,H) row-major [k][n]
              const float* __restrict__ fcw,    // (1,H)
              const float* __restrict__ fcb,    // (1)
              float* __restrict__ out)          // (B,1)
{
    extern __shared__ char smem[];
    char*     ldsW = smem;
    _Float16* hb   = reinterpret_cast<_Float16*>(smem + HB_OFF);
    float*    red  = reinterpret_cast<float*>(smem + RED_OFF);

    const int tid  = threadIdx.x;
    const int w    = tid >> 6;
    const int lane = tid & 63;
    const int l15  = lane & 15;
    const int quad = lane >> 4;
    const int b    = blockIdx.x;

    // ---- Prologue: gather B-frags (W column slices in MFMA B layout) ----
    // B-frag for (n-tile nt, k-tile kt): lane holds B[k = 32*kt + quad*8 + jj][n = 64w+16nt+l15]
    half8_t breg[NT][RKT];
#pragma unroll
    for (int nt = 0; nt < NT; ++nt) {
        const int col = 64 * w + 16 * nt + l15;
#pragma unroll
        for (int kt = 0; kt < KT; ++kt) {
            const int k0 = 32 * kt + quad * 8;
            H8U u;
#pragma unroll
            for (int jj = 0; jj < 8; ++jj)
                u.e[jj] = (_Float16)Whh[(size_t)(k0 + jj) * HDIM + col];
            if (kt < RKT) {
                breg[nt][kt] = u.v;
            } else {
                *reinterpret_cast<uint4*>(
                    ldsW + (size_t)(((w * NT + nt) * LKT + (kt - RKT)) * 64 + lane) * 16) = u.u4;
            }
        }
    }

    // ---- init h slot 0 = 0 ----
    hb[tid] = (_Float16)0.0f;
    __syncthreads();

    const _Float16* xhrow = xh + (size_t)b * TSTEPS * HDIM;

    float hout[NT] = {0.f, 0.f, 0.f, 0.f};
    for (int t = 0; t < TSTEPS; ++t) {
        const int cur = t & 1;
        const int nxt = cur ^ 1;

        // prefetch this step's xh (consumed after the MFMA block; ~700cyc hiding)
        _Float16 xv[NT];
#pragma unroll
        for (int nt = 0; nt < NT; ++nt)
            xv[nt] = xhrow[t * HDIM + 64 * w + 16 * nt + l15];

        float4_t acc[NT];
#pragma unroll
        for (int nt = 0; nt < NT; ++nt) acc[nt] = (float4_t){0.f, 0.f, 0.f, 0.f};

        // A-frag base: lane holds A[m=l15][k = 32*kt + quad*8 + jj] ; for M=1 only m=0 rows
        // matter -> address ignores l15 (16-way LDS broadcast, conflict-free).
        const char* abase = smem + HB_OFF + cur * 1024 + quad * 16;

#pragma unroll
        for (int kt = 0; kt < RKT; ++kt) {
            H8U a;
            a.u4 = *reinterpret_cast<const uint4*>(abase + kt * 64);
#pragma unroll
            for (int nt = 0; nt < NT; ++nt)
                acc[nt] = __builtin_amdgcn_mfma_f32_16x16x32_f16(a.v, breg[nt][kt], acc[nt], 0, 0, 0);
        }
#pragma unroll
        for (int ktl = 0; ktl < LKT; ++ktl) {
            H8U a;
            a.u4 = *reinterpret_cast<const uint4*>(abase + (RKT + ktl) * 64);
#pragma unroll
            for (int nt = 0; nt < NT; ++nt) {
                H8U bb;
                bb.u4 = *reinterpret_cast<const uint4*>(
                    ldsW + (size_t)(((w * NT + nt) * LKT + ktl) * 64 + lane) * 16);
                acc[nt] = __builtin_amdgcn_mfma_f32_16x16x32_f16(a.v, bb.v, acc[nt], 0, 0, 0);
            }
        }

        // D row 0 lives in acc[nt][0] on lanes 0..15 (col = 64w+16nt+lane).
#pragma unroll
        for (int nt = 0; nt < NT; ++nt)
            hout[nt] = fast_tanh(acc[nt][0] + (float)xv[nt]);

        if (lane < 16) {
#pragma unroll
            for (int nt = 0; nt < NT; ++nt)
                hb[nxt * HDIM + 64 * w + 16 * nt + lane] = (_Float16)hout[nt];
        }
        __syncthreads();
    }

    // ---- Epilogue: out[b] = sum h_T[j]*fcw[j] + fcb ----
    float partial = 0.0f;
    if (lane < 16) {
#pragma unroll
        for (int nt = 0; nt < NT; ++nt)
            partial += hout[nt] * fcw[64 * w + 16 * nt + lane];
    }
#pragma unroll
    for (int off = 32; off >= 1; off >>= 1)
        partial += __shfl_down(partial, off, 64);
    if (lane == 0) red[w] = partial;
    __syncthreads();
    if (tid == 0) {
        float s = 0.0f;
#pragma unroll
        for (int i = 0; i < WAVES; ++i) s += red[i];
        out[b] = s + fcb[0];
    }
}

// ============================= fused fallback (R2-proven, emergency only) =============================
#define F_RP   216
#define F_RC   54
#define F_LC   18
#define F_LSTR 19
#define F_LDSW_BYTES (512 * F_LSTR * 16)
#define F_HBUF_OFF   F_LDSW_BYTES
#define F_HBUF_ELEMS 640
#define F_RED_OFF    (F_HBUF_OFF + 2 * F_HBUF_ELEMS * 2)
#define F_SMEM_BYTES (F_RED_OFF + 64)

__device__ __forceinline__ float fdot2(half2_t a, half2_t b, float c) {
#if __has_builtin(__builtin_amdgcn_fdot2)
    return __builtin_amdgcn_fdot2(a, b, c, false);
#else
    return c + (float)a[0] * (float)b[0] + (float)a[1] * (float)b[1];
#endif
}

__device__ __forceinline__ float ldW(const float* __restrict__ Whh,
                                     const float* __restrict__ Wxh, int k, int j) {
    return k < HDIM ? Whh[(size_t)k * HDIM + j] : Wxh[(size_t)(k - HDIM) * HDIM + j];
}

__global__ __attribute__((amdgpu_flat_work_group_size(NTH, NTH), amdgpu_waves_per_eu(2, 2)))
void rnn_fused(const float* __restrict__ x, const float* __restrict__ Wxh,
               const float* __restrict__ Whh, const float* __restrict__ bias,
               const float* __restrict__ fcw, const float* __restrict__ fcb,
               float* __restrict__ out)
{
    extern __shared__ char smem[];
    uint4*    ldsW = reinterpret_cast<uint4*>(smem);
    _Float16* hbuf = reinterpret_cast<_Float16*>(smem + F_HBUF_OFF);
    float*    red  = reinterpret_cast<float*>(smem + F_RED_OFF);

    const int j = threadIdx.x;
    const int b = blockIdx.x;

    half2_t wreg[F_RP];
#pragma unroll
    for (int p = 0; p < F_RP; ++p) {
        const int k = 2 * p;
        half2_t w;
        w[0] = (_Float16)Whh[(size_t)k * HDIM + j];
        w[1] = (_Float16)Whh[(size_t)(k + 1) * HDIM + j];
        wreg[p] = w;
    }
#pragma unroll
    for (int cc = 0; cc < F_LC; ++cc) {
        H8U u;
#pragma unroll
        for (int q = 0; q < 4; ++q) {
            const int k0 = 432 + 8 * cc + 2 * q;
            half2_t w;
            w[0] = (_Float16)ldW(Whh, Wxh, k0, j);
            w[1] = (_Float16)ldW(Whh, Wxh, k0 + 1, j);
            u.p[q] = w;
        }
        ldsW[j * F_LSTR + cc] = u.u4;
    }

    const float bj   = bias[j];
    const float fcwj = fcw[j];

    hbuf[j] = (_Float16)0.0f;
    if (j < IDIM) hbuf[HDIM + j] = (_Float16)x[((size_t)b * TSTEPS + 0) * IDIM + j];
    __syncthreads();

    float hval = 0.0f;
    for (int t = 0; t < TSTEPS; ++t) {
        const int cur = t & 1;
        const int nxt = cur ^ 1;
        const _Float16* hbp = hbuf + cur * F_HBUF_ELEMS;

        float xvv = 0.0f;
        const bool do_x = (j < IDIM) && (t + 1 < TSTEPS);
        if (do_x) xvv = x[((size_t)b * TSTEPS + (t + 1)) * IDIM + j];

        float a0 = bj, a1 = 0.0f, a2 = 0.0f, a3 = 0.0f;
#pragma unroll
        for (int c = 0; c < F_RC; ++c) {
            H8U u;
            u.v = *reinterpret_cast<const half8_t*>(hbp + 8 * c);
            a0 = fdot2(u.p[0], wreg[4 * c + 0], a0);
            a1 = fdot2(u.p[1], wreg[4 * c + 1], a1);
            a2 = fdot2(u.p[2], wreg[4 * c + 2], a2);
            a3 = fdot2(u.p[3], wreg[4 * c + 3], a3);
        }
#pragma unroll
        for (int cc = 0; cc < F_LC; ++cc) {
            H8U u, wv;
            u.v   = *reinterpret_cast<const half8_t*>(hbp + 8 * (F_RC + cc));
            wv.u4 = ldsW[j * F_LSTR + cc];
            a0 = fdot2(u.p[0], wv.p[0], a0);
            a1 = fdot2(u.p[1], wv.p[1], a1);
            a2 = fdot2(u.p[2], wv.p[2], a2);
            a3 = fdot2(u.p[3], wv.p[3], a3);
        }
        hval = fast_tanh((a0 + a1) + (a2 + a3));

        hbuf[nxt * F_HBUF_ELEMS + j] = (_Float16)hval;
        if (do_x) hbuf[nxt * F_HBUF_ELEMS + HDIM + j] = (_Float16)xvv;
        __syncthreads();
    }

    float partial = hval * fcwj;
#pragma unroll
    for (int off = 32; off >= 1; off >>= 1)
        partial += __shfl_down(partial, off, 64);
    if ((j & 63) == 0) red[j >> 6] = partial;
    __syncthreads();
    if (j == 0) {
        float s = 0.0f;
#pragma unroll
        for (int wv = 0; wv < 8; ++wv) s += red[wv];
        out[b] = s + fcb[0];
    }
}

// ============================= host =============================
extern "C" void kernel_launch(void* const* d_in, const int* in_sizes, int n_in,
                              void* d_out, int out_size, void* d_ws, size_t ws_size,
                              hipStream_t stream) {
    const float* x    = (const float*)d_in[0];
    const float* Wxh  = (const float*)d_in[1];
    const float* Whh  = (const float*)d_in[2];
    const float* bias = (const float*)d_in[3];
    const float* fcw  = (const float*)d_in[4];
    const float* fcb  = (const float*)d_in[5];
    float* out = (float*)d_out;

    const size_t xh_bytes = (size_t)BATCH * TSTEPS * HDIM * sizeof(_Float16);  // 134 MB
    if (ws_size >= xh_bytes) {
        hipFuncSetAttribute(reinterpret_cast<const void*>(rnn_mfma),
                            hipFuncAttributeMaxDynamicSharedMemorySize, SMEM_BYTES);
        _Float16* xh = (_Float16*)d_ws;
        xh_gemm<<<(BATCH * TSTEPS) / XH_ROWS, NTH, 0, stream>>>(x, Wxh, bias, xh);
        rnn_mfma<<<BATCH, NTH, SMEM_BYTES, stream>>>(xh, Whh, fcw, fcb, out);
    } else {
        hipFuncSetAttribute(reinterpret_cast<const void*>(rnn_fused),
                            hipFuncAttributeMaxDynamicSharedMemorySize, F_SMEM_BYTES);
        rnn_fused<<<BATCH, NTH, F_SMEM_BYTES, stream>>>(x, Wxh, Whh, bias, fcw, fcb, out);
    }
}